// Round 9
// baseline (959.751 us; speedup 1.0000x reference)
//
#include <hip/hip_runtime.h>

// SpikeLinear: out = LIF_scan( x @ W^T + bias ) over T=8 timesteps.
//
// Numerics (DO NOT CHANGE): must reproduce numpy/OpenBLAS sgemm bit-for-bit
// because the spike threshold (memb > 1.0) is discontinuous. OpenBLAS
// accumulates each C element as a strict sequential fp32 FMA chain over
// ascending k, blocked by kc=384: each panel accumulates from zero in
// registers, then C += panel (fp32 add) in ascending panel order, then fp32
// bias add and fp32 LIF scan. Verified absmax == 0.0 in rounds 3 and 8.
//
// Perf lineage:
//  r3/r8: 4-col tile, 2-barrier LDS loop, (256,4): 851us, VGPR 64, no spill,
//      VALUBusy 70%, occupancy 33% -- grid-starved (1024 blocks = 4/CU).
//  r4-r7: pressure/pipelining attempts all regressed (spill or stall).
//  r8: K-split needed 335 MB of ws -> ws_size was smaller -> fallback ran.
//  r9 (this): COLUMN-SLICED K-split. The panel fold is independent per
//      output column, so slice OUT into groups of NW cols; per slice:
//      phase 1 = 11 independent panel-GEMMs (grid (NW/128)x32x11, r3 inner
//      loop minus fold logic, panels 0..9 -> ws, panel 10 -> out in spike
//      layout), phase 2 = fold in exact BLAS order + bias + LIF scan.
//      ws needed = 10*BT*NW*4 (NW=2048:168MB, 1024:84MB, 512:42MB, 256:21MB);
//      pick largest NW that fits. Fallback: verified r3 kernel.

constexpr int TSTEPS = 8;
constexpr int BK     = 16;
constexpr int TILE_M = 64;    // 8 batches * 8 timesteps
constexpr int TILE_N = 128;   // output columns per block
constexpr int KC     = 384;   // OpenBLAS SGEMM_DEFAULT_Q on x86-64

// ---------------------------------------------------------------- phase 1 --
__global__ __launch_bounds__(256, 4)
void spike_panel_gemm(const float* __restrict__ x,
                      const float* __restrict__ w,
                      float* __restrict__ panels,   // ws: panels 0..np-2, NW cols
                      float* __restrict__ out,      // last panel, spike layout
                      int slice0, int NW,
                      int B, int IN, int OUT, int npanels)
{
    __shared__ float xs[BK][TILE_M + 4];
    __shared__ float wsh[BK][TILE_N + 4];

    const int tid = threadIdx.x;
    const int tx  = tid & 31;    // column group: 4 consecutive outputs
    const int ty  = tid >> 5;    // batch row within tile (owns all 8 t)

    const int m0 = blockIdx.y * TILE_M;
    const int n0 = slice0 + blockIdx.x * TILE_N;
    const int p  = blockIdx.z;
    const int ks = p * KC;
    const int ke = (ks + KC < IN) ? (ks + KC) : IN;

    float acc[TSTEPS][4];        // this panel's accumulator (from zero)
    #pragma unroll
    for (int t = 0; t < TSTEPS; ++t)
        #pragma unroll
        for (int c = 0; c < 4; ++c) acc[t][c] = 0.f;

    const int sr = tid >> 2;         // 0..63
    const int sk = (tid & 3) * 4;    // 0,4,8,12

    const float* xrow  = x + (size_t)(m0 + sr) * IN + sk;
    const float* wrow0 = w + (size_t)(n0 + sr) * IN + sk;
    const float* wrow1 = w + (size_t)(n0 + 64 + sr) * IN + sk;

    for (int kk = ks; kk < ke; kk += BK) {
        const float4 xv  = *(const float4*)(xrow  + kk);
        const float4 wv0 = *(const float4*)(wrow0 + kk);
        const float4 wv1 = *(const float4*)(wrow1 + kk);
        __syncthreads();
        xs[sk+0][sr] = xv.x;  xs[sk+1][sr] = xv.y;
        xs[sk+2][sr] = xv.z;  xs[sk+3][sr] = xv.w;
        wsh[sk+0][sr]    = wv0.x; wsh[sk+1][sr]    = wv0.y;
        wsh[sk+2][sr]    = wv0.z; wsh[sk+3][sr]    = wv0.w;
        wsh[sk+0][sr+64] = wv1.x; wsh[sk+1][sr+64] = wv1.y;
        wsh[sk+2][sr+64] = wv1.z; wsh[sk+3][sr+64] = wv1.w;
        __syncthreads();

        #pragma unroll
        for (int k = 0; k < BK; ++k) {
            float xr[TSTEPS];
            *(float4*)&xr[0] = *(const float4*)&xs[k][ty*8];
            *(float4*)&xr[4] = *(const float4*)&xs[k][ty*8 + 4];
            float wr[4];
            *(float4*)&wr[0] = *(const float4*)&wsh[k][tx*4];
            #pragma unroll
            for (int t = 0; t < TSTEPS; ++t)
                #pragma unroll
                for (int c = 0; c < 4; ++c)
                    acc[t][c] = fmaf(xr[t], wr[c], acc[t][c]);
        }
    }

    const int bg = blockIdx.y * 8 + ty;   // global batch index
    const int cs = blockIdx.x * TILE_N + tx * 4;   // col within slice
    if (p < npanels - 1) {
        // panels 0..np-2: m-major rows (b*8 + t), NW-wide, slot p in ws
        float* pb = panels + ((size_t)p * B * TSTEPS) * NW;
        #pragma unroll
        for (int t = 0; t < TSTEPS; ++t) {
            const int m = bg * TSTEPS + t;
            *(float4*)(pb + (size_t)m * NW + cs) = *(float4*)&acc[t][0];
        }
    } else {
        // last panel -> out with SPIKE row mapping (t*B + b): phase 2's
        // reader thread == writer thread (no cross-thread hazard).
        const int o0 = n0 + tx * 4;
        #pragma unroll
        for (int t = 0; t < TSTEPS; ++t)
            *(float4*)(out + ((size_t)t * B + bg) * OUT + o0) = *(float4*)&acc[t][0];
    }
}

// ---------------------------------------------------------------- phase 2 --
__global__ __launch_bounds__(256)
void spike_fold_scan(const float* __restrict__ panels,
                     const float* __restrict__ bias,
                     float* __restrict__ out,
                     int slice0, int NW,
                     int B, int OUT, int npanels)
{
    const int b = blockIdx.y;
    const size_t psz = (size_t)B * TSTEPS * NW;
    const int nc4 = NW / 4;

    for (int c4 = blockIdx.x * 256 + threadIdx.x; c4 < nc4;
         c4 += gridDim.x * 256) {
        const int cs   = c4 * 4;          // col within slice
        const int gcol = slice0 + cs;     // global col

        // v = panel0; v += panel1 ... += panel(np-2)  (exact BLAS order)
        float4 v[TSTEPS];
        #pragma unroll
        for (int t = 0; t < TSTEPS; ++t)
            v[t] = *(const float4*)(panels + (size_t)(b*TSTEPS + t) * NW + cs);
        for (int p = 1; p < npanels - 1; ++p) {
            const float* pb = panels + (size_t)p * psz;
            #pragma unroll
            for (int t = 0; t < TSTEPS; ++t) {
                const float4 u = *(const float4*)(pb + (size_t)(b*TSTEPS + t) * NW + cs);
                v[t].x += u.x; v[t].y += u.y; v[t].z += u.z; v[t].w += u.w;
            }
        }
        // last panel from out (spike layout, owned by this thread)
        #pragma unroll
        for (int t = 0; t < TSTEPS; ++t) {
            const float4 u = *(const float4*)(out + ((size_t)t * B + b) * OUT + gcol);
            v[t].x += u.x; v[t].y += u.y; v[t].z += u.z; v[t].w += u.w;
        }

        const float4 bb = *(const float4*)(bias + gcol);
        float memb[4] = {0.f, 0.f, 0.f, 0.f};
        #pragma unroll
        for (int t = 0; t < TSTEPS; ++t) {
            float pre[4] = {v[t].x + bb.x, v[t].y + bb.y,
                            v[t].z + bb.z, v[t].w + bb.w};
            float4 sp;
            float* spp = (float*)&sp;
            #pragma unroll
            for (int c = 0; c < 4; ++c) {
                memb[c] += pre[c];                       // VTHR = 1.0 (exact)
                float s = (memb[c] > 1.0f) ? 1.0f : 0.0f;
                memb[c] *= (1.0f - s);                   // reset to zero
                spp[c] = s;
            }
            *(float4*)(out + ((size_t)t * B + b) * OUT + gcol) = sp;
        }
    }
}

// ------------------------------------------------- fallback: r3 (verified) --
__global__ __launch_bounds__(256, 4)
void spike_linear_f32seq(const float* __restrict__ x,
                         const float* __restrict__ w,
                         const float* __restrict__ bias,
                         float* __restrict__ out,
                         int B, int IN, int OUT)
{
    __shared__ float xs[BK][TILE_M + 4];
    __shared__ float ws[BK][TILE_N + 4];

    const int tid = threadIdx.x;
    const int tx  = tid & 31;
    const int ty  = tid >> 5;

    const int m0 = blockIdx.y * TILE_M;
    const int n0 = blockIdx.x * TILE_N;

    float acc_tot[TSTEPS][4];
    float acc_blk[TSTEPS][4];
    #pragma unroll
    for (int t = 0; t < TSTEPS; ++t)
        #pragma unroll
        for (int c = 0; c < 4; ++c) { acc_tot[t][c] = 0.f; acc_blk[t][c] = 0.f; }

    const int sr = tid >> 2;
    const int sk = (tid & 3) * 4;

    const float* xrow  = x + (size_t)(m0 + sr) * IN + sk;
    const float* wrow0 = w + (size_t)(n0 + sr) * IN + sk;
    const float* wrow1 = w + (size_t)(n0 + 64 + sr) * IN + sk;

    for (int kk = 0; kk < IN; kk += BK) {
        if (kk > 0 && (kk % KC) == 0) {
            #pragma unroll
            for (int t = 0; t < TSTEPS; ++t)
                #pragma unroll
                for (int c = 0; c < 4; ++c) {
                    acc_tot[t][c] += acc_blk[t][c];
                    acc_blk[t][c] = 0.f;
                }
        }
        const float4 xv  = *(const float4*)(xrow  + kk);
        const float4 wv0 = *(const float4*)(wrow0 + kk);
        const float4 wv1 = *(const float4*)(wrow1 + kk);
        __syncthreads();
        xs[sk+0][sr] = xv.x;  xs[sk+1][sr] = xv.y;
        xs[sk+2][sr] = xv.z;  xs[sk+3][sr] = xv.w;
        ws[sk+0][sr]    = wv0.x; ws[sk+1][sr]    = wv0.y;
        ws[sk+2][sr]    = wv0.z; ws[sk+3][sr]    = wv0.w;
        ws[sk+0][sr+64] = wv1.x; ws[sk+1][sr+64] = wv1.y;
        ws[sk+2][sr+64] = wv1.z; ws[sk+3][sr+64] = wv1.w;
        __syncthreads();

        #pragma unroll
        for (int k = 0; k < BK; ++k) {
            float xr[TSTEPS];
            *(float4*)&xr[0] = *(const float4*)&xs[k][ty*8];
            *(float4*)&xr[4] = *(const float4*)&xs[k][ty*8 + 4];
            float wr[4];
            *(float4*)&wr[0] = *(const float4*)&ws[k][tx*4];
            #pragma unroll
            for (int t = 0; t < TSTEPS; ++t)
                #pragma unroll
                for (int c = 0; c < 4; ++c)
                    acc_blk[t][c] = fmaf(xr[t], wr[c], acc_blk[t][c]);
        }
    }
    #pragma unroll
    for (int t = 0; t < TSTEPS; ++t)
        #pragma unroll
        for (int c = 0; c < 4; ++c)
            acc_tot[t][c] += acc_blk[t][c];

    const int bg = blockIdx.y * 8 + ty;
    const int o0 = n0 + tx * 4;
    const float4 bv = *(const float4*)(bias + o0);
    const float bb[4] = {bv.x, bv.y, bv.z, bv.w};
    float memb[4] = {0.f, 0.f, 0.f, 0.f};
    #pragma unroll
    for (int t = 0; t < TSTEPS; ++t) {
        float4 sp;
        float* spp = (float*)&sp;
        #pragma unroll
        for (int c = 0; c < 4; ++c) {
            float pre = acc_tot[t][c] + bb[c];
            memb[c] += pre;
            float s = (memb[c] > 1.0f) ? 1.0f : 0.0f;
            memb[c] *= (1.0f - s);
            spp[c] = s;
        }
        *(float4*)(out + ((size_t)t * B + bg) * OUT + o0) = sp;
    }
}

extern "C" void kernel_launch(void* const* d_in, const int* in_sizes, int n_in,
                              void* d_out, int out_size, void* d_ws, size_t ws_size,
                              hipStream_t stream)
{
    const float* x    = (const float*)d_in[0];
    const float* w    = (const float*)d_in[1];
    const float* bias = (const float*)d_in[2];
    float* out = (float*)d_out;

    const int OUT = in_sizes[2];            // 4096
    const int IN  = in_sizes[1] / OUT;      // 4096
    const int BT  = in_sizes[0] / IN;       // 2048
    const int B   = BT / TSTEPS;            // 256

    const int npanels = (IN + KC - 1) / KC; // 11

    // pick the widest column slice whose panel storage fits ws
    int NW = 0;
    for (int cand = 4096; cand >= 256; cand >>= 1) {
        if ((OUT % cand) == 0 &&
            (size_t)(npanels - 1) * BT * cand * sizeof(float) <= ws_size) {
            NW = cand;
            break;
        }
    }

    if (NW >= 256 && npanels >= 2) {
        float* panels = (float*)d_ws;
        const int nslices = OUT / NW;
        for (int s = 0; s < nslices; ++s) {
            const int slice0 = s * NW;
            dim3 g1(NW / TILE_N, BT / TILE_M, npanels);
            spike_panel_gemm<<<g1, 256, 0, stream>>>(x, w, panels, out,
                                                     slice0, NW, B, IN, OUT,
                                                     npanels);
            int gx = NW / 1024; if (gx < 1) gx = 1;
            dim3 g2(gx, B);
            spike_fold_scan<<<g2, 256, 0, stream>>>(panels, bias, out,
                                                    slice0, NW, B, OUT,
                                                    npanels);
        }
    } else {
        dim3 grid(OUT / TILE_N, BT / TILE_M);          // (32, 32)
        spike_linear_f32seq<<<grid, 256, 0, stream>>>(x, w, bias, out, B, IN, OUT);
    }
}

// Round 10
// 891.680 us; speedup vs baseline: 1.0763x; 1.0763x over previous
//
#include <hip/hip_runtime.h>

// SpikeLinear: out = LIF_scan( x @ W^T + bias ) over T=8 timesteps.
//
// Numerics (DO NOT CHANGE): must reproduce numpy/OpenBLAS sgemm bit-for-bit
// because the spike threshold (memb > 1.0) is discontinuous. OpenBLAS
// accumulates each C element as a strict sequential fp32 FMA chain over
// ascending k, blocked by kc=384: each panel accumulates from zero in
// registers, then C += panel (fp32 add) in ascending panel order, then fp32
// bias add and fp32 LIF scan. Verified absmax == 0.0 in rounds 3, 8, 9.
//
// Perf lineage:
//  r3/r8: monolithic 4-col tile -> 851us. r9: K-split 4-col -> 959us.
//  Both sit at ~2.1-2.3x the fp32-FMA issue floor (437us): LDS-read-pipe
//  bound (3 ds_read_b128 per 32 FMAs). r4/r5 showed 8x8 + dual-acc spills;
//  the K-split removes the second acc set, making 8x8 feasible:
//  r10 (this): panel kernel with 8x8 thread tile (TILE_N=256) -> 4 b128
//  reads per 64 FMAs (-33% LDS insts/FMA), single acc[8][8], (256,2),
//  r3's 2-barrier single-buffer loop (no dbuf/prefetch -- r6/r7 lesson).

constexpr int TSTEPS = 8;
constexpr int BK     = 16;
constexpr int TILE_M = 64;    // 8 batches * 8 timesteps
constexpr int TILE_NP= 256;   // panel-kernel tile: 8 cols per thread
constexpr int TILE_N = 128;   // fallback-kernel tile
constexpr int KC     = 384;   // OpenBLAS SGEMM_DEFAULT_Q on x86-64

// ---------------------------------------------------------------- phase 1 --
__global__ __launch_bounds__(256, 2)
void spike_panel_gemm(const float* __restrict__ x,
                      const float* __restrict__ w,
                      float* __restrict__ panels,   // ws: panels 0..np-2, NW cols
                      float* __restrict__ out,      // last panel, spike layout
                      int slice0, int NW,
                      int B, int IN, int OUT, int npanels)
{
    __shared__ float xs[BK][TILE_M + 4];
    __shared__ float wsh[BK][TILE_NP + 8];

    const int tid = threadIdx.x;
    const int tx  = tid & 31;    // owns cols tx*4..+3 and 128+tx*4..+3
    const int ty  = tid >> 5;    // batch row within tile (owns all 8 t)

    const int m0 = blockIdx.y * TILE_M;
    const int n0 = slice0 + blockIdx.x * TILE_NP;
    const int p  = blockIdx.z;
    const int ks = p * KC;
    const int ke = (ks + KC < IN) ? (ks + KC) : IN;

    float acc[TSTEPS][8];        // single accumulator set (K-split enables this)
    #pragma unroll
    for (int t = 0; t < TSTEPS; ++t)
        #pragma unroll
        for (int c = 0; c < 8; ++c) acc[t][c] = 0.f;

    const int sr = tid >> 2;         // 0..63
    const int sk = (tid & 3) * 4;    // 0,4,8,12

    const float* xrow  = x + (size_t)(m0 + sr) * IN + sk;
    const float* wrow0 = w + (size_t)(n0 +       sr) * IN + sk;
    const float* wrow1 = w + (size_t)(n0 +  64 + sr) * IN + sk;
    const float* wrow2 = w + (size_t)(n0 + 128 + sr) * IN + sk;
    const float* wrow3 = w + (size_t)(n0 + 192 + sr) * IN + sk;

    for (int kk = ks; kk < ke; kk += BK) {
        const float4 xv  = *(const float4*)(xrow  + kk);
        const float4 wv0 = *(const float4*)(wrow0 + kk);
        const float4 wv1 = *(const float4*)(wrow1 + kk);
        const float4 wv2 = *(const float4*)(wrow2 + kk);
        const float4 wv3 = *(const float4*)(wrow3 + kk);
        __syncthreads();
        xs[sk+0][sr] = xv.x;  xs[sk+1][sr] = xv.y;
        xs[sk+2][sr] = xv.z;  xs[sk+3][sr] = xv.w;
        wsh[sk+0][sr]     = wv0.x; wsh[sk+1][sr]     = wv0.y;
        wsh[sk+2][sr]     = wv0.z; wsh[sk+3][sr]     = wv0.w;
        wsh[sk+0][sr+64]  = wv1.x; wsh[sk+1][sr+64]  = wv1.y;
        wsh[sk+2][sr+64]  = wv1.z; wsh[sk+3][sr+64]  = wv1.w;
        wsh[sk+0][sr+128] = wv2.x; wsh[sk+1][sr+128] = wv2.y;
        wsh[sk+2][sr+128] = wv2.z; wsh[sk+3][sr+128] = wv2.w;
        wsh[sk+0][sr+192] = wv3.x; wsh[sk+1][sr+192] = wv3.y;
        wsh[sk+2][sr+192] = wv3.z; wsh[sk+3][sr+192] = wv3.w;
        __syncthreads();

        #pragma unroll
        for (int k = 0; k < BK; ++k) {
            float xr[TSTEPS], wr[8];
            *(float4*)&xr[0] = *(const float4*)&xs[k][ty*8];
            *(float4*)&xr[4] = *(const float4*)&xs[k][ty*8 + 4];
            *(float4*)&wr[0] = *(const float4*)&wsh[k][tx*4];
            *(float4*)&wr[4] = *(const float4*)&wsh[k][128 + tx*4];
            #pragma unroll
            for (int t = 0; t < TSTEPS; ++t)
                #pragma unroll
                for (int c = 0; c < 8; ++c)
                    acc[t][c] = fmaf(xr[t], wr[c], acc[t][c]);
        }
    }

    const int bg = blockIdx.y * 8 + ty;             // global batch index
    const int cs = blockIdx.x * TILE_NP + tx * 4;   // col within slice
    if (p < npanels - 1) {
        // panels 0..np-2: m-major rows (b*8 + t), NW-wide, slot p in ws
        float* pb = panels + ((size_t)p * B * TSTEPS) * NW;
        #pragma unroll
        for (int t = 0; t < TSTEPS; ++t) {
            const int m = bg * TSTEPS + t;
            *(float4*)(pb + (size_t)m * NW + cs)       = *(float4*)&acc[t][0];
            *(float4*)(pb + (size_t)m * NW + cs + 128) = *(float4*)&acc[t][4];
        }
    } else {
        // last panel -> out with SPIKE row mapping (t*B + b): phase 2's
        // reader thread == writer thread (no cross-thread hazard).
        const int o0 = n0 + tx * 4;
        #pragma unroll
        for (int t = 0; t < TSTEPS; ++t) {
            float* op = out + ((size_t)t * B + bg) * OUT + o0;
            *(float4*)op         = *(float4*)&acc[t][0];
            *(float4*)(op + 128) = *(float4*)&acc[t][4];
        }
    }
}

// ---------------------------------------------------------------- phase 2 --
__global__ __launch_bounds__(256)
void spike_fold_scan(const float* __restrict__ panels,
                     const float* __restrict__ bias,
                     float* __restrict__ out,
                     int slice0, int NW,
                     int B, int OUT, int npanels)
{
    const int b = blockIdx.y;
    const size_t psz = (size_t)B * TSTEPS * NW;
    const int nc4 = NW / 4;

    for (int c4 = blockIdx.x * 256 + threadIdx.x; c4 < nc4;
         c4 += gridDim.x * 256) {
        const int cs   = c4 * 4;          // col within slice
        const int gcol = slice0 + cs;     // global col

        // v = panel0; v += panel1 ... += panel(np-2)  (exact BLAS order)
        float4 v[TSTEPS];
        #pragma unroll
        for (int t = 0; t < TSTEPS; ++t)
            v[t] = *(const float4*)(panels + (size_t)(b*TSTEPS + t) * NW + cs);
        for (int p = 1; p < npanels - 1; ++p) {
            const float* pb = panels + (size_t)p * psz;
            #pragma unroll
            for (int t = 0; t < TSTEPS; ++t) {
                const float4 u = *(const float4*)(pb + (size_t)(b*TSTEPS + t) * NW + cs);
                v[t].x += u.x; v[t].y += u.y; v[t].z += u.z; v[t].w += u.w;
            }
        }
        // last panel from out (spike layout, owned by this thread)
        #pragma unroll
        for (int t = 0; t < TSTEPS; ++t) {
            const float4 u = *(const float4*)(out + ((size_t)t * B + b) * OUT + gcol);
            v[t].x += u.x; v[t].y += u.y; v[t].z += u.z; v[t].w += u.w;
        }

        const float4 bb = *(const float4*)(bias + gcol);
        float memb[4] = {0.f, 0.f, 0.f, 0.f};
        #pragma unroll
        for (int t = 0; t < TSTEPS; ++t) {
            float pre[4] = {v[t].x + bb.x, v[t].y + bb.y,
                            v[t].z + bb.z, v[t].w + bb.w};
            float4 sp;
            float* spp = (float*)&sp;
            #pragma unroll
            for (int c = 0; c < 4; ++c) {
                memb[c] += pre[c];                       // VTHR = 1.0 (exact)
                float s = (memb[c] > 1.0f) ? 1.0f : 0.0f;
                memb[c] *= (1.0f - s);                   // reset to zero
                spp[c] = s;
            }
            *(float4*)(out + ((size_t)t * B + b) * OUT + gcol) = sp;
        }
    }
}

// ------------------------------------------------- fallback: r3 (verified) --
__global__ __launch_bounds__(256, 4)
void spike_linear_f32seq(const float* __restrict__ x,
                         const float* __restrict__ w,
                         const float* __restrict__ bias,
                         float* __restrict__ out,
                         int B, int IN, int OUT)
{
    __shared__ float xs[BK][TILE_M + 4];
    __shared__ float ws[BK][TILE_N + 4];

    const int tid = threadIdx.x;
    const int tx  = tid & 31;
    const int ty  = tid >> 5;

    const int m0 = blockIdx.y * TILE_M;
    const int n0 = blockIdx.x * TILE_N;

    float acc_tot[TSTEPS][4];
    float acc_blk[TSTEPS][4];
    #pragma unroll
    for (int t = 0; t < TSTEPS; ++t)
        #pragma unroll
        for (int c = 0; c < 4; ++c) { acc_tot[t][c] = 0.f; acc_blk[t][c] = 0.f; }

    const int sr = tid >> 2;
    const int sk = (tid & 3) * 4;

    const float* xrow  = x + (size_t)(m0 + sr) * IN + sk;
    const float* wrow0 = w + (size_t)(n0 + sr) * IN + sk;
    const float* wrow1 = w + (size_t)(n0 + 64 + sr) * IN + sk;

    for (int kk = 0; kk < IN; kk += BK) {
        if (kk > 0 && (kk % KC) == 0) {
            #pragma unroll
            for (int t = 0; t < TSTEPS; ++t)
                #pragma unroll
                for (int c = 0; c < 4; ++c) {
                    acc_tot[t][c] += acc_blk[t][c];
                    acc_blk[t][c] = 0.f;
                }
        }
        const float4 xv  = *(const float4*)(xrow  + kk);
        const float4 wv0 = *(const float4*)(wrow0 + kk);
        const float4 wv1 = *(const float4*)(wrow1 + kk);
        __syncthreads();
        xs[sk+0][sr] = xv.x;  xs[sk+1][sr] = xv.y;
        xs[sk+2][sr] = xv.z;  xs[sk+3][sr] = xv.w;
        ws[sk+0][sr]    = wv0.x; ws[sk+1][sr]    = wv0.y;
        ws[sk+2][sr]    = wv0.z; ws[sk+3][sr]    = wv0.w;
        ws[sk+0][sr+64] = wv1.x; ws[sk+1][sr+64] = wv1.y;
        ws[sk+2][sr+64] = wv1.z; ws[sk+3][sr+64] = wv1.w;
        __syncthreads();

        #pragma unroll
        for (int k = 0; k < BK; ++k) {
            float xr[TSTEPS];
            *(float4*)&xr[0] = *(const float4*)&xs[k][ty*8];
            *(float4*)&xr[4] = *(const float4*)&xs[k][ty*8 + 4];
            float wr[4];
            *(float4*)&wr[0] = *(const float4*)&ws[k][tx*4];
            #pragma unroll
            for (int t = 0; t < TSTEPS; ++t)
                #pragma unroll
                for (int c = 0; c < 4; ++c)
                    acc_blk[t][c] = fmaf(xr[t], wr[c], acc_blk[t][c]);
        }
    }
    #pragma unroll
    for (int t = 0; t < TSTEPS; ++t)
        #pragma unroll
        for (int c = 0; c < 4; ++c)
            acc_tot[t][c] += acc_blk[t][c];

    const int bg = blockIdx.y * 8 + ty;
    const int o0 = n0 + tx * 4;
    const float4 bv = *(const float4*)(bias + o0);
    const float bb[4] = {bv.x, bv.y, bv.z, bv.w};
    float memb[4] = {0.f, 0.f, 0.f, 0.f};
    #pragma unroll
    for (int t = 0; t < TSTEPS; ++t) {
        float4 sp;
        float* spp = (float*)&sp;
        #pragma unroll
        for (int c = 0; c < 4; ++c) {
            float pre = acc_tot[t][c] + bb[c];
            memb[c] += pre;
            float s = (memb[c] > 1.0f) ? 1.0f : 0.0f;
            memb[c] *= (1.0f - s);
            spp[c] = s;
        }
        *(float4*)(out + ((size_t)t * B + bg) * OUT + o0) = sp;
    }
}

extern "C" void kernel_launch(void* const* d_in, const int* in_sizes, int n_in,
                              void* d_out, int out_size, void* d_ws, size_t ws_size,
                              hipStream_t stream)
{
    const float* x    = (const float*)d_in[0];
    const float* w    = (const float*)d_in[1];
    const float* bias = (const float*)d_in[2];
    float* out = (float*)d_out;

    const int OUT = in_sizes[2];            // 4096
    const int IN  = in_sizes[1] / OUT;      // 4096
    const int BT  = in_sizes[0] / IN;       // 2048
    const int B   = BT / TSTEPS;            // 256

    const int npanels = (IN + KC - 1) / KC; // 11

    // pick the widest column slice whose panel storage fits ws
    int NW = 0;
    for (int cand = 4096; cand >= 256; cand >>= 1) {
        if ((OUT % cand) == 0 &&
            (size_t)(npanels - 1) * BT * cand * sizeof(float) <= ws_size) {
            NW = cand;
            break;
        }
    }

    if (NW >= 256 && npanels >= 2) {
        float* panels = (float*)d_ws;
        const int nslices = OUT / NW;
        for (int s = 0; s < nslices; ++s) {
            const int slice0 = s * NW;
            dim3 g1(NW / TILE_NP, BT / TILE_M, npanels);
            spike_panel_gemm<<<g1, 256, 0, stream>>>(x, w, panels, out,
                                                     slice0, NW, B, IN, OUT,
                                                     npanels);
            int gx = NW / 1024; if (gx < 1) gx = 1;
            dim3 g2(gx, B);
            spike_fold_scan<<<g2, 256, 0, stream>>>(panels, bias, out,
                                                    slice0, NW, B, OUT,
                                                    npanels);
        }
    } else {
        dim3 grid(OUT / TILE_N, BT / TILE_M);          // (32, 32)
        spike_linear_f32seq<<<grid, 256, 0, stream>>>(x, w, bias, out, B, IN, OUT);
    }
}

// Round 11
// 811.918 us; speedup vs baseline: 1.1821x; 1.0982x over previous
//
#include <hip/hip_runtime.h>

// SpikeLinear: out = LIF_scan( x @ W^T + bias ) over T=8 timesteps.
//
// Numerics (DO NOT CHANGE): must reproduce numpy/OpenBLAS sgemm bit-for-bit
// because the spike threshold (memb > 1.0) is discontinuous. OpenBLAS
// accumulates each C element as a strict sequential fp32 FMA chain over
// ascending k, blocked by kc=384: each panel accumulates from zero in
// registers, then C += panel (fp32 add) in ascending panel order, then fp32
// bias add and fp32 LIF scan. Verified absmax == 0.0 in rounds 3, 8, 9, 10.
//
// Perf lineage:
//  r3..r10: every scalar-fmaf structure lands at 850-990us ~= 2.1x the
//  437us scalar-issue floor; m07 shows scalar v_fma_f32 ceiling ~103 TF
//  (65% of the 157.3 TF spec). The spec FP32 rate on CDNA3/4 comes from
//  packed v_pk_fma_f32 (2 fp32 FMA/lane/inst), which hipcc never emits
//  from scalar fmaf.
//  r11 (this): r10 structure (K-split panels, 8x8 tile, single acc set,
//  (256,2)) with the inner loop as 32 v_pk_fma_f32 per k. Each packed
//  component is a single-rounded IEEE FMA == fmaf, so two adjacent-column
//  chains share one instruction with bit-identical results. x is broadcast
//  from a pair word via op_sel (PK_LO/PK_HI variants), W and acc use the
//  natural pair words.

typedef float v2f __attribute__((ext_vector_type(2)));

// acc = x.word0 * w + acc   (x broadcast from word0 of the pair)
#define PK_LO(a, x, wv)                                                       \
    asm("v_pk_fma_f32 %0, %1, %2, %0 op_sel:[0,0,0] op_sel_hi:[0,1,1]"        \
        : "+v"(a) : "v"(x), "v"(wv))
// acc = x.word1 * w + acc   (x broadcast from word1 of the pair)
#define PK_HI(a, x, wv)                                                       \
    asm("v_pk_fma_f32 %0, %1, %2, %0 op_sel:[1,0,0] op_sel_hi:[1,1,1]"        \
        : "+v"(a) : "v"(x), "v"(wv))

constexpr int TSTEPS = 8;
constexpr int BK     = 16;
constexpr int TILE_M = 64;    // 8 batches * 8 timesteps
constexpr int TILE_NP= 256;   // panel-kernel tile: 8 cols per thread
constexpr int TILE_N = 128;   // fallback-kernel tile
constexpr int KC     = 384;   // OpenBLAS SGEMM_DEFAULT_Q on x86-64

// ---------------------------------------------------------------- phase 1 --
__global__ __launch_bounds__(256, 2)
void spike_panel_gemm(const float* __restrict__ x,
                      const float* __restrict__ w,
                      float* __restrict__ panels,   // ws: panels 0..np-2, NW cols
                      float* __restrict__ out,      // last panel, spike layout
                      int slice0, int NW,
                      int B, int IN, int OUT, int npanels)
{
    __shared__ float xs[BK][TILE_M + 4];
    __shared__ float wsh[BK][TILE_NP + 8];

    const int tid = threadIdx.x;
    const int tx  = tid & 31;    // owns cols tx*4..+3 and 128+tx*4..+3
    const int ty  = tid >> 5;    // batch row within tile (owns all 8 t)

    const int m0 = blockIdx.y * TILE_M;
    const int n0 = slice0 + blockIdx.x * TILE_NP;
    const int p  = blockIdx.z;
    const int ks = p * KC;
    const int ke = (ks + KC < IN) ? (ks + KC) : IN;

    // acc[t][pair]: pair 0={c0,c1}, 1={c2,c3} (cols cs..), 2,3 = cols cs+128..
    v2f acc[TSTEPS][4];
    #pragma unroll
    for (int t = 0; t < TSTEPS; ++t)
        #pragma unroll
        for (int q = 0; q < 4; ++q) acc[t][q] = (v2f){0.f, 0.f};

    const int sr = tid >> 2;         // 0..63
    const int sk = (tid & 3) * 4;    // 0,4,8,12

    const float* xrow  = x + (size_t)(m0 + sr) * IN + sk;
    const float* wrow0 = w + (size_t)(n0 +       sr) * IN + sk;
    const float* wrow1 = w + (size_t)(n0 +  64 + sr) * IN + sk;
    const float* wrow2 = w + (size_t)(n0 + 128 + sr) * IN + sk;
    const float* wrow3 = w + (size_t)(n0 + 192 + sr) * IN + sk;

    for (int kk = ks; kk < ke; kk += BK) {
        const float4 xv  = *(const float4*)(xrow  + kk);
        const float4 wv0 = *(const float4*)(wrow0 + kk);
        const float4 wv1 = *(const float4*)(wrow1 + kk);
        const float4 wv2 = *(const float4*)(wrow2 + kk);
        const float4 wv3 = *(const float4*)(wrow3 + kk);
        __syncthreads();
        xs[sk+0][sr] = xv.x;  xs[sk+1][sr] = xv.y;
        xs[sk+2][sr] = xv.z;  xs[sk+3][sr] = xv.w;
        wsh[sk+0][sr]     = wv0.x; wsh[sk+1][sr]     = wv0.y;
        wsh[sk+2][sr]     = wv0.z; wsh[sk+3][sr]     = wv0.w;
        wsh[sk+0][sr+64]  = wv1.x; wsh[sk+1][sr+64]  = wv1.y;
        wsh[sk+2][sr+64]  = wv1.z; wsh[sk+3][sr+64]  = wv1.w;
        wsh[sk+0][sr+128] = wv2.x; wsh[sk+1][sr+128] = wv2.y;
        wsh[sk+2][sr+128] = wv2.z; wsh[sk+3][sr+128] = wv2.w;
        wsh[sk+0][sr+192] = wv3.x; wsh[sk+1][sr+192] = wv3.y;
        wsh[sk+2][sr+192] = wv3.z; wsh[sk+3][sr+192] = wv3.w;
        __syncthreads();

        #pragma unroll
        for (int k = 0; k < BK; ++k) {
            // xp[tp] = {x[2tp], x[2tp+1]}; broadcast via op_sel
            v2f xp[4], wv[4];
            *(float4*)&xp[0] = *(const float4*)&xs[k][ty*8];
            *(float4*)&xp[2] = *(const float4*)&xs[k][ty*8 + 4];
            *(float4*)&wv[0] = *(const float4*)&wsh[k][tx*4];
            *(float4*)&wv[2] = *(const float4*)&wsh[k][128 + tx*4];
            #pragma unroll
            for (int tp = 0; tp < 4; ++tp) {
                #pragma unroll
                for (int q = 0; q < 4; ++q) {
                    PK_LO(acc[2*tp  ][q], xp[tp], wv[q]);
                    PK_HI(acc[2*tp+1][q], xp[tp], wv[q]);
                }
            }
        }
    }

    const int bg = blockIdx.y * 8 + ty;             // global batch index
    const int cs = blockIdx.x * TILE_NP + tx * 4;   // col within slice
    if (p < npanels - 1) {
        // panels 0..np-2: m-major rows (b*8 + t), NW-wide, slot p in ws
        float* pb = panels + ((size_t)p * B * TSTEPS) * NW;
        #pragma unroll
        for (int t = 0; t < TSTEPS; ++t) {
            const int m = bg * TSTEPS + t;
            float4 lo, hi;
            *(v2f*)&lo.x = acc[t][0]; *(v2f*)&lo.z = acc[t][1];
            *(v2f*)&hi.x = acc[t][2]; *(v2f*)&hi.z = acc[t][3];
            *(float4*)(pb + (size_t)m * NW + cs)       = lo;
            *(float4*)(pb + (size_t)m * NW + cs + 128) = hi;
        }
    } else {
        // last panel -> out with SPIKE row mapping (t*B + b): phase 2's
        // reader thread == writer thread (no cross-thread hazard).
        const int o0 = n0 + tx * 4;
        #pragma unroll
        for (int t = 0; t < TSTEPS; ++t) {
            float4 lo, hi;
            *(v2f*)&lo.x = acc[t][0]; *(v2f*)&lo.z = acc[t][1];
            *(v2f*)&hi.x = acc[t][2]; *(v2f*)&hi.z = acc[t][3];
            float* op = out + ((size_t)t * B + bg) * OUT + o0;
            *(float4*)op         = lo;
            *(float4*)(op + 128) = hi;
        }
    }
}

// ---------------------------------------------------------------- phase 2 --
__global__ __launch_bounds__(256)
void spike_fold_scan(const float* __restrict__ panels,
                     const float* __restrict__ bias,
                     float* __restrict__ out,
                     int slice0, int NW,
                     int B, int OUT, int npanels)
{
    const int b = blockIdx.y;
    const size_t psz = (size_t)B * TSTEPS * NW;
    const int nc4 = NW / 4;

    for (int c4 = blockIdx.x * 256 + threadIdx.x; c4 < nc4;
         c4 += gridDim.x * 256) {
        const int cs   = c4 * 4;          // col within slice
        const int gcol = slice0 + cs;     // global col

        // v = panel0; v += panel1 ... += panel(np-2)  (exact BLAS order)
        float4 v[TSTEPS];
        #pragma unroll
        for (int t = 0; t < TSTEPS; ++t)
            v[t] = *(const float4*)(panels + (size_t)(b*TSTEPS + t) * NW + cs);
        for (int p = 1; p < npanels - 1; ++p) {
            const float* pb = panels + (size_t)p * psz;
            #pragma unroll
            for (int t = 0; t < TSTEPS; ++t) {
                const float4 u = *(const float4*)(pb + (size_t)(b*TSTEPS + t) * NW + cs);
                v[t].x += u.x; v[t].y += u.y; v[t].z += u.z; v[t].w += u.w;
            }
        }
        // last panel from out (spike layout, owned by this thread)
        #pragma unroll
        for (int t = 0; t < TSTEPS; ++t) {
            const float4 u = *(const float4*)(out + ((size_t)t * B + b) * OUT + gcol);
            v[t].x += u.x; v[t].y += u.y; v[t].z += u.z; v[t].w += u.w;
        }

        const float4 bb = *(const float4*)(bias + gcol);
        float memb[4] = {0.f, 0.f, 0.f, 0.f};
        #pragma unroll
        for (int t = 0; t < TSTEPS; ++t) {
            float pre[4] = {v[t].x + bb.x, v[t].y + bb.y,
                            v[t].z + bb.z, v[t].w + bb.w};
            float4 sp;
            float* spp = (float*)&sp;
            #pragma unroll
            for (int c = 0; c < 4; ++c) {
                memb[c] += pre[c];                       // VTHR = 1.0 (exact)
                float s = (memb[c] > 1.0f) ? 1.0f : 0.0f;
                memb[c] *= (1.0f - s);                   // reset to zero
                spp[c] = s;
            }
            *(float4*)(out + ((size_t)t * B + b) * OUT + gcol) = sp;
        }
    }
}

// ------------------------------------------------- fallback: r3 (verified) --
__global__ __launch_bounds__(256, 4)
void spike_linear_f32seq(const float* __restrict__ x,
                         const float* __restrict__ w,
                         const float* __restrict__ bias,
                         float* __restrict__ out,
                         int B, int IN, int OUT)
{
    __shared__ float xs[BK][TILE_M + 4];
    __shared__ float ws[BK][TILE_N + 4];

    const int tid = threadIdx.x;
    const int tx  = tid & 31;
    const int ty  = tid >> 5;

    const int m0 = blockIdx.y * TILE_M;
    const int n0 = blockIdx.x * TILE_N;

    float acc_tot[TSTEPS][4];
    float acc_blk[TSTEPS][4];
    #pragma unroll
    for (int t = 0; t < TSTEPS; ++t)
        #pragma unroll
        for (int c = 0; c < 4; ++c) { acc_tot[t][c] = 0.f; acc_blk[t][c] = 0.f; }

    const int sr = tid >> 2;
    const int sk = (tid & 3) * 4;

    const float* xrow  = x + (size_t)(m0 + sr) * IN + sk;
    const float* wrow0 = w + (size_t)(n0 + sr) * IN + sk;
    const float* wrow1 = w + (size_t)(n0 + 64 + sr) * IN + sk;

    for (int kk = 0; kk < IN; kk += BK) {
        if (kk > 0 && (kk % KC) == 0) {
            #pragma unroll
            for (int t = 0; t < TSTEPS; ++t)
                #pragma unroll
                for (int c = 0; c < 4; ++c) {
                    acc_tot[t][c] += acc_blk[t][c];
                    acc_blk[t][c] = 0.f;
                }
        }
        const float4 xv  = *(const float4*)(xrow  + kk);
        const float4 wv0 = *(const float4*)(wrow0 + kk);
        const float4 wv1 = *(const float4*)(wrow1 + kk);
        __syncthreads();
        xs[sk+0][sr] = xv.x;  xs[sk+1][sr] = xv.y;
        xs[sk+2][sr] = xv.z;  xs[sk+3][sr] = xv.w;
        ws[sk+0][sr]    = wv0.x; ws[sk+1][sr]    = wv0.y;
        ws[sk+2][sr]    = wv0.z; ws[sk+3][sr]    = wv0.w;
        ws[sk+0][sr+64] = wv1.x; ws[sk+1][sr+64] = wv1.y;
        ws[sk+2][sr+64] = wv1.z; ws[sk+3][sr+64] = wv1.w;
        __syncthreads();

        #pragma unroll
        for (int k = 0; k < BK; ++k) {
            float xr[TSTEPS];
            *(float4*)&xr[0] = *(const float4*)&xs[k][ty*8];
            *(float4*)&xr[4] = *(const float4*)&xs[k][ty*8 + 4];
            float wr[4];
            *(float4*)&wr[0] = *(const float4*)&ws[k][tx*4];
            #pragma unroll
            for (int t = 0; t < TSTEPS; ++t)
                #pragma unroll
                for (int c = 0; c < 4; ++c)
                    acc_blk[t][c] = fmaf(xr[t], wr[c], acc_blk[t][c]);
        }
    }
    #pragma unroll
    for (int t = 0; t < TSTEPS; ++t)
        #pragma unroll
        for (int c = 0; c < 4; ++c)
            acc_tot[t][c] += acc_blk[t][c];

    const int bg = blockIdx.y * 8 + ty;
    const int o0 = n0 + tx * 4;
    const float4 bv = *(const float4*)(bias + o0);
    const float bb[4] = {bv.x, bv.y, bv.z, bv.w};
    float memb[4] = {0.f, 0.f, 0.f, 0.f};
    #pragma unroll
    for (int t = 0; t < TSTEPS; ++t) {
        float4 sp;
        float* spp = (float*)&sp;
        #pragma unroll
        for (int c = 0; c < 4; ++c) {
            float pre = acc_tot[t][c] + bb[c];
            memb[c] += pre;
            float s = (memb[c] > 1.0f) ? 1.0f : 0.0f;
            memb[c] *= (1.0f - s);
            spp[c] = s;
        }
        *(float4*)(out + ((size_t)t * B + bg) * OUT + o0) = sp;
    }
}

extern "C" void kernel_launch(void* const* d_in, const int* in_sizes, int n_in,
                              void* d_out, int out_size, void* d_ws, size_t ws_size,
                              hipStream_t stream)
{
    const float* x    = (const float*)d_in[0];
    const float* w    = (const float*)d_in[1];
    const float* bias = (const float*)d_in[2];
    float* out = (float*)d_out;

    const int OUT = in_sizes[2];            // 4096
    const int IN  = in_sizes[1] / OUT;      // 4096
    const int BT  = in_sizes[0] / IN;       // 2048
    const int B   = BT / TSTEPS;            // 256

    const int npanels = (IN + KC - 1) / KC; // 11

    // pick the widest column slice whose panel storage fits ws
    int NW = 0;
    for (int cand = 4096; cand >= 256; cand >>= 1) {
        if ((OUT % cand) == 0 &&
            (size_t)(npanels - 1) * BT * cand * sizeof(float) <= ws_size) {
            NW = cand;
            break;
        }
    }

    if (NW >= 256 && npanels >= 2) {
        float* panels = (float*)d_ws;
        const int nslices = OUT / NW;
        for (int s = 0; s < nslices; ++s) {
            const int slice0 = s * NW;
            dim3 g1(NW / TILE_NP, BT / TILE_M, npanels);
            spike_panel_gemm<<<g1, 256, 0, stream>>>(x, w, panels, out,
                                                     slice0, NW, B, IN, OUT,
                                                     npanels);
            int gx = NW / 1024; if (gx < 1) gx = 1;
            dim3 g2(gx, B);
            spike_fold_scan<<<g2, 256, 0, stream>>>(panels, bias, out,
                                                    slice0, NW, B, OUT,
                                                    npanels);
        }
    } else {
        dim3 grid(OUT / TILE_N, BT / TILE_M);          // (32, 32)
        spike_linear_f32seq<<<grid, 256, 0, stream>>>(x, w, bias, out, B, IN, OUT);
    }
}